// Round 1
// baseline (3535.836 us; speedup 1.0000x reference)
//
#include <hip/hip_runtime.h>
#include <math.h>

#define BB 4
#define N0 4096
#define NEWP 1152
#define GD 256
#define HD 128
#define KSEL 64
#define NSTEPS 10
#define NMAX (N0 + NSTEPS*NEWP)   /* 15616 */

/* ---- workspace layout (float offsets) ---- */
#define OFF_CANVAS 0
#define OFF_SCORES (OFF_CANVAS + BB*NMAX*3)        /* 187392 */
#define OFF_D2     (OFF_SCORES + BB*NMAX)          /* +62464 */
#define OFF_GMAX   (OFF_D2 + BB*NMAX)              /* +62464 (uint) */
#define OFF_H      (OFF_GMAX + BB*GD)
#define OFF_C      (OFF_H + BB*HD)
#define OFF_ACC    (OFF_C + BB*HD)
#define OFF_CENTER (OFF_ACC + 16)
#define OFF_W2T    (OFF_CENTER + 16)
#define OFF_W3T    (OFF_W2T + 128*64)
#define OFF_F2     (OFF_W3T + 256*128)
#define WS_FLOATS  (OFF_F2 + BB*N0*128)            /* ~2.45M floats */

__device__ __forceinline__ unsigned enc_f(float f){
  unsigned u = __float_as_uint(f);
  return (u & 0x80000000u) ? ~u : (u | 0x80000000u);
}
__device__ __forceinline__ float dec_f(unsigned e){
  unsigned u = (e & 0x80000000u) ? (e & 0x7fffffffu) : ~e;
  return __uint_as_float(u);
}
__device__ __forceinline__ float sigm(float x){ return 1.f/(1.f+expf(-x)); }

__device__ __forceinline__ float block_sum(float v, volatile float* red){
#pragma unroll
  for (int s=32;s>0;s>>=1) v += __shfl_down(v, s, 64);
  int lane = threadIdx.x & 63, w = threadIdx.x >> 6, nw = blockDim.x >> 6;
  __syncthreads();
  if (lane==0) red[w] = v;
  __syncthreads();
  if (w==0){
    float x = (lane < nw) ? red[lane] : 0.f;
#pragma unroll
    for (int s=8;s>0;s>>=1) x += __shfl_down(x, s, 64);
    if (lane==0) red[0] = x;
  }
  __syncthreads();
  float r = red[0];
  __syncthreads();
  return r;
}
__device__ __forceinline__ float block_max(float v, volatile float* red){
#pragma unroll
  for (int s=32;s>0;s>>=1) v = fmaxf(v, __shfl_down(v, s, 64));
  int lane = threadIdx.x & 63, w = threadIdx.x >> 6, nw = blockDim.x >> 6;
  __syncthreads();
  if (lane==0) red[w] = v;
  __syncthreads();
  if (w==0){
    float x = (lane < nw) ? red[lane] : -3.4e38f;
#pragma unroll
    for (int s=8;s>0;s>>=1) x = fmaxf(x, __shfl_down(x, s, 64));
    if (lane==0) red[0] = x;
  }
  __syncthreads();
  float r = red[0];
  __syncthreads();
  return r;
}

/* transpose enc_w2 (64x128)->w2t[j*64+k], enc_w3 (128x256)->w3t[d*128+k] */
__global__ __launch_bounds__(256) void prep_kernel(
    const float* __restrict__ w2, const float* __restrict__ w3,
    float* __restrict__ w2t, float* __restrict__ w3t)
{
  int i = blockIdx.x*256 + threadIdx.x;
  if (i < 128*64){ int j = i>>6, k = i&63; w2t[i] = w2[k*128 + j]; }
  if (i < 256*128){ int d = i>>7, k = i&127; w3t[i] = w3[k*256 + d]; }
}

__global__ __launch_bounds__(256) void init_kernel(
    const float* __restrict__ points, float* __restrict__ canvas,
    float* __restrict__ h, float* __restrict__ c,
    unsigned* __restrict__ gmax, float* __restrict__ acc)
{
  int i = blockIdx.x*256 + threadIdx.x;
  if (i < BB*N0*3){
    int b = i / (N0*3);
    int r = i - b*(N0*3);
    canvas[(size_t)b*NMAX*3 + r] = points[i];
  }
  if (i < BB*HD){ h[i] = 0.f; c[i] = 0.f; }
  if (i < BB*GD) gmax[i] = 0u;
  if (i < 16) acc[i] = 0.f;
}

/* encoder layers 1+2 for new points; jc = half of the 128 outputs */
__global__ __launch_bounds__(256) void enc12_kernel(
    const float* __restrict__ canvas, const float* __restrict__ w1,
    const float* __restrict__ b1, const float* __restrict__ w2t,
    const float* __restrict__ b2, float* __restrict__ f2buf,
    int off, int M)
{
  int b = blockIdx.y;
  int jc = blockIdx.z;
  int i = blockIdx.x*256 + threadIdx.x;
  int ii = (i < M) ? i : 0;
  const float* p = canvas + (size_t)(b*NMAX + off + ii)*3;
  float p0 = p[0], p1 = p[1], p2 = p[2];
  float f1[64];
#pragma unroll
  for (int j=0;j<64;j++)
    f1[j] = fmaxf(0.f, b1[j] + p0*w1[j] + p1*w1[64+j] + p2*w1[128+j]);
  float* outp = f2buf + (size_t)(b*N0 + ii)*128 + jc*64;
#pragma unroll
  for (int j=0;j<64;j++){
    float a = b2[jc*64 + j];
    const float* wr = w2t + (jc*64 + j)*64;
#pragma unroll
    for (int k=0;k<64;k++) a += f1[k]*wr[k];
    if (i < M) outp[j] = fmaxf(0.f, a);
  }
}

/* encoder layer 3 + running-max pool; dc = 32-dim chunk of the 256 outputs */
__global__ __launch_bounds__(256) void enc3_kernel(
    const float* __restrict__ f2buf, const float* __restrict__ w3t,
    const float* __restrict__ b3, unsigned* __restrict__ gmax, int M)
{
  int b = blockIdx.y;
  int dc = blockIdx.z;
  int i = blockIdx.x*256 + threadIdx.x;
  bool act = i < M;
  int ii = act ? i : 0;
  const float* fr = f2buf + (size_t)(b*N0 + ii)*128;
  float f2[128];
#pragma unroll
  for (int k=0;k<128;k++) f2[k] = fr[k];
  for (int d0=0; d0<32; d0++){
    int d = dc*32 + d0;
    float a = b3[d];
    const float* wr = w3t + d*128;
#pragma unroll
    for (int k=0;k<128;k++) a += f2[k]*wr[k];
    if (!act) a = -3.4e38f;
#pragma unroll
    for (int s=32;s>0;s>>=1) a = fmaxf(a, __shfl_down(a, s, 64));
    if ((threadIdx.x & 63) == 0) atomicMax(&gmax[b*GD + d], enc_f(a));
  }
}

/* attention scores; per-batch bias from gfeat/h computed per block */
__global__ __launch_bounds__(256) void scores_kernel(
    const float* __restrict__ canvas, const float* __restrict__ aw1,
    const float* __restrict__ ab1, const float* __restrict__ aw2,
    const float* __restrict__ ab2, const unsigned* __restrict__ gmax,
    const float* __restrict__ h, float* __restrict__ scores, int N)
{
  __shared__ float sBatt[128];
  int b = blockIdx.y;
  int tid = threadIdx.x;
  if (tid < 128){
    float a = ab1[tid];
    for (int k=0;k<GD;k++) a += dec_f(gmax[b*GD+k]) * aw1[(3+k)*128 + tid];
    for (int k=0;k<HD;k++) a += h[b*HD+k] * aw1[(3+GD+k)*128 + tid];
    sBatt[tid] = a;
  }
  __syncthreads();
  int i = blockIdx.x*256 + tid;
  if (i < N){
    const float* p = canvas + (size_t)(b*NMAX + i)*3;
    float p0 = p[0], p1 = p[1], p2 = p[2];
    float s = ab2[0];
    for (int j=0;j<128;j++){
      float t = sBatt[j] + p0*aw1[j] + p1*aw1[128+j] + p2*aw1[256+j];
      s += fmaxf(t, 0.f) * aw2[j];
    }
    scores[(size_t)b*NMAX + i] = s;
  }
}

/* per-batch: softmax+center, radix-select top-64 patch, LSTM update */
__global__ __launch_bounds__(1024) void stepA_kernel(
    const float* __restrict__ canvas, const float* __restrict__ scores,
    float* __restrict__ d2buf, const unsigned* __restrict__ gmax,
    float* __restrict__ h, float* __restrict__ c,
    const float* __restrict__ wih, const float* __restrict__ whh,
    const float* __restrict__ bih, const float* __restrict__ bhh,
    float* __restrict__ centerbuf, int N)
{
  __shared__ float red[32];
  __shared__ float sC[3], sPF[3];
  __shared__ unsigned hist[256];
  __shared__ int sSelBin, sSelK, tieCnt;
  __shared__ int tieIdx[256];
  __shared__ float sIn[GD+6];
  __shared__ float sHold[HD];
  __shared__ float sGates[4*HD];

  int b = blockIdx.x;
  int tid = threadIdx.x;
  const float* sc = scores + (size_t)b*NMAX;
  float* dd = d2buf + (size_t)b*NMAX;
  const float* cv = canvas + (size_t)b*NMAX*3;

  /* --- softmax over scores + weighted center --- */
  float m = -3.4e38f;
  for (int i=tid;i<N;i+=1024) m = fmaxf(m, sc[i]);
  m = block_max(m, red);
  float se=0.f, wx=0.f, wy=0.f, wz=0.f;
  for (int i=tid;i<N;i+=1024){
    float e = expf(sc[i]-m);
    const float* p = cv + (size_t)i*3;
    se += e; wx += e*p[0]; wy += e*p[1]; wz += e*p[2];
  }
  se = block_sum(se, red);
  wx = block_sum(wx, red);
  wy = block_sum(wy, red);
  wz = block_sum(wz, red);
  if (tid==0){ sC[0]=wx/se; sC[1]=wy/se; sC[2]=wz/se; }
  __syncthreads();
  float cx=sC[0], cy=sC[1], cz=sC[2];
  if (tid<3) centerbuf[b*3+tid] = sC[tid];

  /* --- squared distances --- */
  for (int i=tid;i<N;i+=1024){
    const float* p = cv + (size_t)i*3;
    float dx=p[0]-cx, dy=p[1]-cy, dz=p[2]-cz;
    dd[i] = dx*dx + dy*dy + dz*dz;
  }
  __threadfence_block();
  __syncthreads();

  /* --- radix select: 64th smallest d2 (bits are monotonic for d2>=0) --- */
  int kneed = KSEL;
  unsigned prefix = 0;
  for (int pass=0; pass<4; pass++){
    int shift = 24 - 8*pass;
    if (tid < 256) hist[tid] = 0;
    __syncthreads();
    for (int i=tid;i<N;i+=1024){
      unsigned u = __float_as_uint(dd[i]);
      bool ok = (pass==0) ? true : ((u >> (shift+8)) == prefix);
      if (ok) atomicAdd(&hist[(u>>shift)&255], 1u);
    }
    __syncthreads();
    if (tid==0){
      unsigned cum=0; int sel=255, kk=kneed;
      for (int bin=0;bin<256;bin++){
        unsigned nc = cum + hist[bin];
        if ((int)nc >= kk){ sel=bin; kk = kk - (int)cum; break; }
        cum = nc;
      }
      sSelBin = sel; sSelK = kk;
    }
    __syncthreads();
    prefix = (prefix<<8) | (unsigned)sSelBin;
    kneed = sSelK;
    __syncthreads();
  }
  unsigned T = prefix;

  if (tid==0) tieCnt = 0;
  __syncthreads();
  float sx=0.f, sy=0.f, sz=0.f;
  for (int i=tid;i<N;i+=1024){
    unsigned u = __float_as_uint(dd[i]);
    if (u < T){
      const float* p = cv + (size_t)i*3;
      sx += p[0]; sy += p[1]; sz += p[2];
    } else if (u == T){
      int pos = atomicAdd(&tieCnt, 1);
      if (pos < 256) tieIdx[pos] = i;
    }
  }
  __syncthreads();
  sx = block_sum(sx, red);
  sy = block_sum(sy, red);
  sz = block_sum(sz, red);
  if (tid==0){
    int mm = tieCnt < 256 ? tieCnt : 256;
    for (int t=0;t<kneed;t++){
      int best=-1, bi=0x7fffffff;
      for (int q=0;q<mm;q++){ int v = tieIdx[q]; if (v < bi){ bi=v; best=q; } }
      if (best >= 0){
        tieIdx[best] = 0x7fffffff;
        const float* p = cv + (size_t)bi*3;
        sx += p[0]; sy += p[1]; sz += p[2];
      }
    }
    sPF[0] = sx/KSEL - cx; sPF[1] = sy/KSEL - cy; sPF[2] = sz/KSEL - cz;
  }
  __syncthreads();

  /* --- LSTM --- */
  if (tid < GD) sIn[tid] = dec_f(gmax[b*GD + tid]);
  else if (tid < GD+3) sIn[tid] = sC[tid-GD];
  else if (tid < GD+6) sIn[tid] = sPF[tid-GD-3];
  if (tid < HD) sHold[tid] = h[b*HD + tid];
  __syncthreads();
  if (tid < 4*HD){
    float a = bih[tid] + bhh[tid];
    for (int k=0;k<GD+6;k++) a += sIn[k]*wih[k*(4*HD) + tid];
    for (int k=0;k<HD;k++)   a += sHold[k]*whh[k*(4*HD) + tid];
    sGates[tid] = a;
  }
  __syncthreads();
  if (tid < HD){
    float gi = sGates[tid], gf = sGates[HD+tid], gg = sGates[2*HD+tid], go = sGates[3*HD+tid];
    float cn = sigm(gf)*c[b*HD+tid] + sigm(gi)*tanhf(gg);
    float hn = sigm(go)*tanhf(cn);
    c[b*HD+tid] = cn;
    h[b*HD+tid] = hn;
  }
}

/* refinement decoder: new_pts = relu(h@rw1+rb1)@rw2+rb2 -> canvas append */
__global__ __launch_bounds__(256) void refine_kernel(
    float* __restrict__ canvas, const float* __restrict__ h,
    const float* __restrict__ centerbuf,
    const float* __restrict__ rw1, const float* __restrict__ rb1,
    const float* __restrict__ rw2, const float* __restrict__ rb2, int N)
{
  __shared__ float sRf[HD];
  int b = blockIdx.y;
  int tid = threadIdx.x;
  if (tid < HD){
    float a = rb1[tid];
    for (int k=0;k<HD;k++) a += h[b*HD+k]*rw1[k*HD + tid];
    sRf[tid] = fmaxf(a, 0.f);
  }
  __syncthreads();
  int o = blockIdx.x*256 + tid;
  if (o < NEWP*3){
    float a = rb2[o];
    for (int k=0;k<HD;k++) a += sRf[k]*rw2[k*(NEWP*3) + o];
    canvas[((size_t)b*NMAX + N)*3 + o] = a*0.02f + centerbuf[b*3 + (o%3)];
  }
}

#define CTILE 1024
__global__ __launch_bounds__(256) void chamfer_kernel(
    const float* __restrict__ X, const float* __restrict__ Y,
    int Nx, int Ny, int sxb, int syb, float* __restrict__ acc)
{
  __shared__ float sy[CTILE*3];
  __shared__ float red[32];
  int b = blockIdx.y;
  int tid = threadIdx.x;
  int i = blockIdx.x*256 + tid;
  bool act = i < Nx;
  const float* xp = X + (size_t)b*sxb + (size_t)(act?i:0)*3;
  float x0 = xp[0], x1 = xp[1], x2 = xp[2];
  float mn = 3.4e38f;
  const float* yb = Y + (size_t)b*syb;
  for (int y0=0; y0<Ny; y0+=CTILE){
    int tn = min(CTILE, Ny - y0);
    __syncthreads();
    for (int t=tid; t<tn*3; t+=256) sy[t] = yb[(size_t)y0*3 + t];
    __syncthreads();
    if (act){
#pragma unroll 4
      for (int j=0;j<tn;j++){
        float dx = x0 - sy[j*3], dy = x1 - sy[j*3+1], dz = x2 - sy[j*3+2];
        mn = fminf(mn, dx*dx + dy*dy + dz*dz);
      }
    }
  }
  if (!act) mn = 0.f;
  mn = block_sum(mn, red);
  if (tid == 0) atomicAdd(&acc[b], mn);
}

__global__ void finish_kernel(const float* __restrict__ acc, float* __restrict__ out)
{
  if (threadIdx.x == 0 && blockIdx.x == 0){
    float cd1 = 0.f, cd2 = 0.f;
    for (int b=0;b<BB;b++) cd1 += acc[b]/(float)N0 + acc[4+b]/(float)N0;
    for (int b=0;b<BB;b++) cd2 += acc[8+b]/(float)(NSTEPS*NEWP) + acc[12+b]/(float)N0;
    out[0] = 0.1f*(cd1/BB) + 1.0f*(cd2/BB);
  }
}

extern "C" void kernel_launch(void* const* d_in, const int* in_sizes, int n_in,
                              void* d_out, int out_size, void* d_ws, size_t ws_size,
                              hipStream_t stream) {
  (void)in_sizes; (void)n_in; (void)out_size; (void)ws_size;
  const float* points   = (const float*)d_in[0];
  const float* gt       = (const float*)d_in[1];
  const float* enc_w1   = (const float*)d_in[2];
  const float* enc_b1   = (const float*)d_in[3];
  const float* enc_w2   = (const float*)d_in[4];
  const float* enc_b2   = (const float*)d_in[5];
  const float* enc_w3   = (const float*)d_in[6];
  const float* enc_b3   = (const float*)d_in[7];
  const float* att_w1   = (const float*)d_in[8];
  const float* att_b1   = (const float*)d_in[9];
  const float* att_w2   = (const float*)d_in[10];
  const float* att_b2   = (const float*)d_in[11];
  const float* lstm_wih = (const float*)d_in[12];
  const float* lstm_whh = (const float*)d_in[13];
  const float* lstm_bih = (const float*)d_in[14];
  const float* lstm_bhh = (const float*)d_in[15];
  const float* ref_w1   = (const float*)d_in[16];
  const float* ref_b1   = (const float*)d_in[17];
  const float* ref_w2   = (const float*)d_in[18];
  const float* ref_b2   = (const float*)d_in[19];
  float* out = (float*)d_out;

  float* ws      = (float*)d_ws;
  float* canvas  = ws + OFF_CANVAS;
  float* scoresb = ws + OFF_SCORES;
  float* d2b     = ws + OFF_D2;
  unsigned* gmaxp = (unsigned*)(ws + OFF_GMAX);
  float* hb      = ws + OFF_H;
  float* cb      = ws + OFF_C;
  float* acc     = ws + OFF_ACC;
  float* centerb = ws + OFF_CENTER;
  float* w2t     = ws + OFF_W2T;
  float* w3t     = ws + OFF_W3T;
  float* f2buf   = ws + OFF_F2;

  prep_kernel<<<dim3(128), 256, 0, stream>>>(enc_w2, enc_w3, w2t, w3t);
  init_kernel<<<dim3(192), 256, 0, stream>>>(points, canvas, hb, cb, gmaxp, acc);

  for (int t=0; t<NSTEPS; t++){
    int off = (t==0) ? 0 : (N0 + (t-1)*NEWP);
    int M   = (t==0) ? N0 : NEWP;
    int N   = N0 + t*NEWP;
    int nbM = (M + 255)/256;
    int nbN = (N + 255)/256;
    enc12_kernel<<<dim3(nbM, BB, 2), 256, 0, stream>>>(canvas, enc_w1, enc_b1, w2t, enc_b2, f2buf, off, M);
    enc3_kernel<<<dim3(nbM, BB, 8), 256, 0, stream>>>(f2buf, w3t, enc_b3, gmaxp, M);
    scores_kernel<<<dim3(nbN, BB), 256, 0, stream>>>(canvas, att_w1, att_b1, att_w2, att_b2, gmaxp, hb, scoresb, N);
    stepA_kernel<<<dim3(BB), 1024, 0, stream>>>(canvas, scoresb, d2b, gmaxp, hb, cb,
                                                lstm_wih, lstm_whh, lstm_bih, lstm_bhh, centerb, N);
    refine_kernel<<<dim3(14, BB), 256, 0, stream>>>(canvas, hb, centerb, ref_w1, ref_b1, ref_w2, ref_b2, N);
  }

  /* chamfer: (p_input<->gt) and (p_new<->gt) */
  chamfer_kernel<<<dim3(16, BB), 256, 0, stream>>>(canvas,        gt, N0,           N0,           NMAX*3, N0*3,   acc+0);
  chamfer_kernel<<<dim3(16, BB), 256, 0, stream>>>(gt,        canvas, N0,           N0,           N0*3,   NMAX*3, acc+4);
  chamfer_kernel<<<dim3(45, BB), 256, 0, stream>>>(canvas+N0*3,   gt, NSTEPS*NEWP,  N0,           NMAX*3, N0*3,   acc+8);
  chamfer_kernel<<<dim3(16, BB), 256, 0, stream>>>(gt,   canvas+N0*3, N0,           NSTEPS*NEWP,  N0*3,   NMAX*3, acc+12);
  finish_kernel<<<1, 64, 0, stream>>>(acc, out);
}

// Round 2
// 2164.920 us; speedup vs baseline: 1.6332x; 1.6332x over previous
//
#include <hip/hip_runtime.h>
#include <math.h>

#define BB 4
#define N0 4096
#define NEWP 1152
#define GD 256
#define HD 128
#define KSEL 64
#define NSTEPS 10
#define NMAX (N0 + NSTEPS*NEWP)   /* 15616 */
#define NNEW (NSTEPS*NEWP)        /* 11520 */
#define F2S (BB*N0)               /* 16384: stride of f2buf[k][b*N0+i] */

/* ---- workspace layout (float offsets) ---- */
#define OFF_CANVAS 0
#define OFF_SCORES (OFF_CANVAS + BB*NMAX*3)
#define OFF_D2     (OFF_SCORES + BB*NMAX)
#define OFF_GMAX   (OFF_D2 + BB*NMAX)
#define OFF_H      (OFF_GMAX + BB*GD)
#define OFF_C      (OFF_H + BB*HD)
#define OFF_ACC    (OFF_C + BB*HD)
#define OFF_CENTER (OFF_ACC + 16)
#define OFF_W2T    (OFF_CENTER + 16)
#define OFF_BIAS   (OFF_W2T + 128*64)
#define OFF_F2     (OFF_BIAS + BB*128)
#define WS_FLOATS  (OFF_F2 + 128*F2S)   /* ~2.42M floats ~9.7MB */

__device__ __forceinline__ unsigned enc_f(float f){
  unsigned u = __float_as_uint(f);
  return (u & 0x80000000u) ? ~u : (u | 0x80000000u);
}
__device__ __forceinline__ float dec_f(unsigned e){
  unsigned u = (e & 0x80000000u) ? (e & 0x7fffffffu) : ~e;
  return __uint_as_float(u);
}
__device__ __forceinline__ float sigm(float x){ return 1.f/(1.f+expf(-x)); }

__device__ __forceinline__ float block_sum(float v, volatile float* red){
#pragma unroll
  for (int s=32;s>0;s>>=1) v += __shfl_down(v, s, 64);
  int lane = threadIdx.x & 63, w = threadIdx.x >> 6, nw = blockDim.x >> 6;
  __syncthreads();
  if (lane==0) red[w] = v;
  __syncthreads();
  if (w==0){
    float x = (lane < nw) ? red[lane] : 0.f;
#pragma unroll
    for (int s=8;s>0;s>>=1) x += __shfl_down(x, s, 64);
    if (lane==0) red[0] = x;
  }
  __syncthreads();
  float r = red[0];
  __syncthreads();
  return r;
}
__device__ __forceinline__ float block_max(float v, volatile float* red){
#pragma unroll
  for (int s=32;s>0;s>>=1) v = fmaxf(v, __shfl_down(v, s, 64));
  int lane = threadIdx.x & 63, w = threadIdx.x >> 6, nw = blockDim.x >> 6;
  __syncthreads();
  if (lane==0) red[w] = v;
  __syncthreads();
  if (w==0){
    float x = (lane < nw) ? red[lane] : -3.4e38f;
#pragma unroll
    for (int s=8;s>0;s>>=1) x = fmaxf(x, __shfl_down(x, s, 64));
    if (lane==0) red[0] = x;
  }
  __syncthreads();
  float r = red[0];
  __syncthreads();
  return r;
}

/* transpose enc_w2 (64x128)->w2t[j*64+k] */
__global__ __launch_bounds__(256) void prep_kernel(
    const float* __restrict__ w2, float* __restrict__ w2t)
{
  int i = blockIdx.x*256 + threadIdx.x;
  if (i < 128*64){ int j = i>>6, k = i&63; w2t[i] = w2[k*128 + j]; }
}

__global__ __launch_bounds__(256) void init_kernel(
    const float* __restrict__ points, float* __restrict__ canvas,
    float* __restrict__ h, float* __restrict__ c,
    unsigned* __restrict__ gmax)
{
  int i = blockIdx.x*256 + threadIdx.x;
  if (i < BB*N0*3){
    int b = i / (N0*3);
    int r = i - b*(N0*3);
    canvas[(size_t)b*NMAX*3 + r] = points[i];
  }
  if (i < BB*HD){ h[i] = 0.f; c[i] = 0.f; }
  if (i < BB*GD) gmax[i] = 0u;
}

/* encoder layers 1+2 for new points; jc = half of the 128 outputs.
   f2buf layout: [k][b*N0 + i] (feature-major, coalesced both ways) */
__global__ __launch_bounds__(256) void enc12_kernel(
    const float* __restrict__ canvas, const float* __restrict__ w1,
    const float* __restrict__ b1, const float* __restrict__ w2t,
    const float* __restrict__ b2, float* __restrict__ f2buf,
    int off, int M)
{
  int b = blockIdx.y;
  int jc = blockIdx.z;
  int i = blockIdx.x*256 + threadIdx.x;
  int ii = (i < M) ? i : 0;
  const float* p = canvas + (size_t)(b*NMAX + off + ii)*3;
  float p0 = p[0], p1 = p[1], p2 = p[2];
  float f1[64];
#pragma unroll
  for (int j=0;j<64;j++)
    f1[j] = fmaxf(0.f, b1[j] + p0*w1[j] + p1*w1[64+j] + p2*w1[128+j]);
  int base = b*N0 + ii;
#pragma unroll
  for (int j=0;j<64;j++){
    float a = b2[jc*64 + j];
    const float* wr = w2t + (jc*64 + j)*64;
#pragma unroll
    for (int k=0;k<64;k++) a += f1[k]*wr[k];
    if (i < M) f2buf[(size_t)(jc*64 + j)*F2S + base] = fmaxf(0.f, a);
  }
}

/* encoder layer 3 + running-max pool. dc = 64-dim chunk (4 chunks).
   k outer, 64 accumulators in VGPRs — NO per-thread input array (no spill). */
__global__ __launch_bounds__(256) void enc3_kernel(
    const float* __restrict__ f2buf, const float* __restrict__ w3,
    const float* __restrict__ b3, unsigned* __restrict__ gmax, int M)
{
  int b = blockIdx.y;
  int dc = blockIdx.z;
  int i = blockIdx.x*256 + threadIdx.x;
  bool act = i < M;
  int ii = act ? i : 0;
  const float* fp = f2buf + b*N0 + ii;
  float a[64];
#pragma unroll
  for (int d0=0; d0<64; d0++) a[d0] = b3[dc*64 + d0];
  for (int k=0;k<128;k++){
    float fk = fp[(size_t)k*F2S];          /* coalesced */
    const float* wr = w3 + k*256 + dc*64;  /* wave-uniform -> scalar loads */
#pragma unroll
    for (int d0=0; d0<64; d0++) a[d0] += fk * wr[d0];
  }
#pragma unroll
  for (int d0=0; d0<64; d0++){
    float v = act ? a[d0] : -3.4e38f;
#pragma unroll
    for (int s2=32;s2>0;s2>>=1) v = fmaxf(v, __shfl_down(v, s2, 64));
    if ((threadIdx.x & 63) == 0) atomicMax(&gmax[b*GD + dc*64 + d0], enc_f(v));
  }
}

/* per-batch attention bias from gfeat/h — computed ONCE per step */
__global__ __launch_bounds__(128) void attbias_kernel(
    const float* __restrict__ aw1, const float* __restrict__ ab1,
    const unsigned* __restrict__ gmax, const float* __restrict__ h,
    float* __restrict__ bias)
{
  int b = blockIdx.x, tid = threadIdx.x;
  float a = ab1[tid];
  for (int k=0;k<GD;k++) a += dec_f(gmax[b*GD+k]) * aw1[(3+k)*128 + tid];
  for (int k=0;k<HD;k++) a += h[b*HD+k] * aw1[(3+GD+k)*128 + tid];
  bias[b*128+tid] = a;
}

/* attention scores per point */
__global__ __launch_bounds__(256) void scores_kernel(
    const float* __restrict__ canvas, const float* __restrict__ aw1,
    const float* __restrict__ aw2, const float* __restrict__ ab2,
    const float* __restrict__ bias, float* __restrict__ scores, int N)
{
  __shared__ float sBatt[128];
  int b = blockIdx.y;
  int tid = threadIdx.x;
  if (tid < 128) sBatt[tid] = bias[b*128 + tid];
  __syncthreads();
  int i = blockIdx.x*256 + tid;
  if (i < N){
    const float* p = canvas + (size_t)(b*NMAX + i)*3;
    float p0 = p[0], p1 = p[1], p2 = p[2];
    float s = ab2[0];
    for (int j=0;j<128;j++){
      float t = sBatt[j] + p0*aw1[j] + p1*aw1[128+j] + p2*aw1[256+j];
      s += fmaxf(t, 0.f) * aw2[j];
    }
    scores[(size_t)b*NMAX + i] = s;
  }
}

/* per-batch: softmax+center, radix-select top-64 patch, LSTM update */
__global__ __launch_bounds__(1024) void stepA_kernel(
    const float* __restrict__ canvas, const float* __restrict__ scores,
    float* __restrict__ d2buf, const unsigned* __restrict__ gmax,
    float* __restrict__ h, float* __restrict__ c,
    const float* __restrict__ wih, const float* __restrict__ whh,
    const float* __restrict__ bih, const float* __restrict__ bhh,
    float* __restrict__ centerbuf, int N)
{
  __shared__ float red[32];
  __shared__ float sC[3], sPF[3];
  __shared__ unsigned hist[256];
  __shared__ int sSelBin, sSelK, tieCnt;
  __shared__ int tieIdx[256];
  __shared__ float sIn[GD+6];
  __shared__ float sHold[HD];
  __shared__ float sGates[4*HD];

  int b = blockIdx.x;
  int tid = threadIdx.x;
  const float* sc = scores + (size_t)b*NMAX;
  float* dd = d2buf + (size_t)b*NMAX;
  const float* cv = canvas + (size_t)b*NMAX*3;

  float m = -3.4e38f;
  for (int i=tid;i<N;i+=1024) m = fmaxf(m, sc[i]);
  m = block_max(m, red);
  float se=0.f, wx=0.f, wy=0.f, wz=0.f;
  for (int i=tid;i<N;i+=1024){
    float e = expf(sc[i]-m);
    const float* p = cv + (size_t)i*3;
    se += e; wx += e*p[0]; wy += e*p[1]; wz += e*p[2];
  }
  se = block_sum(se, red);
  wx = block_sum(wx, red);
  wy = block_sum(wy, red);
  wz = block_sum(wz, red);
  if (tid==0){ sC[0]=wx/se; sC[1]=wy/se; sC[2]=wz/se; }
  __syncthreads();
  float cx=sC[0], cy=sC[1], cz=sC[2];
  if (tid<3) centerbuf[b*3+tid] = sC[tid];

  for (int i=tid;i<N;i+=1024){
    const float* p = cv + (size_t)i*3;
    float dx=p[0]-cx, dy=p[1]-cy, dz=p[2]-cz;
    dd[i] = dx*dx + dy*dy + dz*dz;
  }
  __syncthreads();

  /* radix select: 64th smallest d2 */
  int kneed = KSEL;
  unsigned prefix = 0;
  for (int pass=0; pass<4; pass++){
    int shift = 24 - 8*pass;
    if (tid < 256) hist[tid] = 0;
    __syncthreads();
    for (int i=tid;i<N;i+=1024){
      unsigned u = __float_as_uint(dd[i]);
      bool ok = (pass==0) ? true : ((u >> (shift+8)) == prefix);
      if (ok) atomicAdd(&hist[(u>>shift)&255], 1u);
    }
    __syncthreads();
    if (tid==0){
      unsigned cum=0; int sel=255, kk=kneed;
      for (int bin=0;bin<256;bin++){
        unsigned nc = cum + hist[bin];
        if ((int)nc >= kk){ sel=bin; kk = kk - (int)cum; break; }
        cum = nc;
      }
      sSelBin = sel; sSelK = kk;
    }
    __syncthreads();
    prefix = (prefix<<8) | (unsigned)sSelBin;
    kneed = sSelK;
    __syncthreads();
  }
  unsigned T = prefix;

  if (tid==0) tieCnt = 0;
  __syncthreads();
  float sx=0.f, sy=0.f, sz=0.f;
  for (int i=tid;i<N;i+=1024){
    unsigned u = __float_as_uint(dd[i]);
    if (u < T){
      const float* p = cv + (size_t)i*3;
      sx += p[0]; sy += p[1]; sz += p[2];
    } else if (u == T){
      int pos = atomicAdd(&tieCnt, 1);
      if (pos < 256) tieIdx[pos] = i;
    }
  }
  __syncthreads();
  sx = block_sum(sx, red);
  sy = block_sum(sy, red);
  sz = block_sum(sz, red);
  if (tid==0){
    int mm = tieCnt < 256 ? tieCnt : 256;
    for (int t=0;t<kneed;t++){
      int best=-1, bi=0x7fffffff;
      for (int q=0;q<mm;q++){ int v = tieIdx[q]; if (v < bi){ bi=v; best=q; } }
      if (best >= 0){
        tieIdx[best] = 0x7fffffff;
        const float* p = cv + (size_t)bi*3;
        sx += p[0]; sy += p[1]; sz += p[2];
      }
    }
    sPF[0] = sx/KSEL - cx; sPF[1] = sy/KSEL - cy; sPF[2] = sz/KSEL - cz;
  }
  __syncthreads();

  /* LSTM */
  if (tid < GD) sIn[tid] = dec_f(gmax[b*GD + tid]);
  else if (tid < GD+3) sIn[tid] = sC[tid-GD];
  else if (tid < GD+6) sIn[tid] = sPF[tid-GD-3];
  if (tid < HD) sHold[tid] = h[b*HD + tid];
  __syncthreads();
  if (tid < 4*HD){
    float a = bih[tid] + bhh[tid];
    for (int k=0;k<GD+6;k++) a += sIn[k]*wih[k*(4*HD) + tid];
    for (int k=0;k<HD;k++)   a += sHold[k]*whh[k*(4*HD) + tid];
    sGates[tid] = a;
  }
  __syncthreads();
  if (tid < HD){
    float gi = sGates[tid], gf = sGates[HD+tid], gg = sGates[2*HD+tid], go = sGates[3*HD+tid];
    float cn = sigm(gf)*c[b*HD+tid] + sigm(gi)*tanhf(gg);
    float hn = sigm(go)*tanhf(cn);
    c[b*HD+tid] = cn;
    h[b*HD+tid] = hn;
  }
}

/* refinement decoder */
__global__ __launch_bounds__(256) void refine_kernel(
    float* __restrict__ canvas, const float* __restrict__ h,
    const float* __restrict__ centerbuf,
    const float* __restrict__ rw1, const float* __restrict__ rb1,
    const float* __restrict__ rw2, const float* __restrict__ rb2, int N)
{
  __shared__ float sRf[HD];
  int b = blockIdx.y;
  int tid = threadIdx.x;
  if (tid < HD){
    float a = rb1[tid];
    for (int k=0;k<HD;k++) a += h[b*HD+k]*rw1[k*HD + tid];
    sRf[tid] = fmaxf(a, 0.f);
  }
  __syncthreads();
  int o = blockIdx.x*256 + tid;
  if (o < NEWP*3){
    float a = rb2[o];
    for (int k=0;k<HD;k++) a += sRf[k]*rw2[k*(NEWP*3) + o];
    canvas[((size_t)b*NMAX + N)*3 + o] = a*0.02f + centerbuf[b*3 + (o%3)];
  }
}

/* ---- chamfer: fused all 4 directions, x- and y-tiled, atomicMin partials ---- */
#define CXT 1024
#define CYT 1024

__global__ __launch_bounds__(256) void chamfer_init_kernel(
    unsigned* __restrict__ minAB, unsigned* __restrict__ minCD)
{
  int i = blockIdx.x*256 + threadIdx.x;
  int nAB = 2*BB*N0;                 /* 32768 */
  int nCD = BB*NNEW + BB*N0;         /* 62464 */
  if (i < nAB) minAB[i] = 0xFFFFFFFFu;
  if (i < nCD) minCD[i] = 0xFFFFFFFFu;
}

__global__ __launch_bounds__(256) void chamfer_kernel(
    const float* __restrict__ canvas, const float* __restrict__ gt,
    unsigned* __restrict__ minAB, unsigned* __restrict__ minCD)
{
  __shared__ float sy[CYT*3];
  int z = blockIdx.z, dir = z>>2, b = z&3;
  int Nx, Ny; const float* X; const float* Y; unsigned* mp;
  if (dir==0){      Nx=N0;   Ny=N0;   X=canvas+(size_t)b*NMAX*3;         Y=gt+(size_t)b*N0*3;              mp=minAB + b*N0; }
  else if (dir==1){ Nx=N0;   Ny=N0;   X=gt+(size_t)b*N0*3;               Y=canvas+(size_t)b*NMAX*3;        mp=minAB + BB*N0 + b*N0; }
  else if (dir==2){ Nx=NNEW; Ny=N0;   X=canvas+((size_t)b*NMAX+N0)*3;    Y=gt+(size_t)b*N0*3;              mp=minCD + b*NNEW; }
  else {            Nx=N0;   Ny=NNEW; X=gt+(size_t)b*N0*3;               Y=canvas+((size_t)b*NMAX+N0)*3;   mp=minCD + BB*NNEW + b*N0; }
  int xbase = blockIdx.x*CXT;
  int ybase = blockIdx.y*CYT;
  if (xbase >= Nx || ybase >= Ny) return;
  int tn = min(CYT, Ny - ybase);
  int tid = threadIdx.x;
  for (int t=tid; t<tn*3; t+=256) sy[t] = Y[(size_t)ybase*3 + t];
  __syncthreads();
  float x0[4], x1[4], x2[4], mn[4];
  int xi[4]; bool va[4];
#pragma unroll
  for (int q=0;q<4;q++){
    int x = xbase + q*256 + tid;
    va[q] = x < Nx;
    int xc = va[q] ? x : 0;
    x0[q]=X[(size_t)xc*3]; x1[q]=X[(size_t)xc*3+1]; x2[q]=X[(size_t)xc*3+2];
    mn[q]=3.4e38f; xi[q]=xc;
  }
#pragma unroll 2
  for (int j=0;j<tn;j++){
    float y0=sy[3*j], y1=sy[3*j+1], y2=sy[3*j+2];   /* broadcast, conflict-free */
#pragma unroll
    for (int q=0;q<4;q++){
      float dx=x0[q]-y0, dy=x1[q]-y1, dz=x2[q]-y2;
      mn[q] = fminf(mn[q], dx*dx + dy*dy + dz*dz);
    }
  }
#pragma unroll
  for (int q=0;q<4;q++)
    if (va[q]) atomicMin(&mp[xi[q]], enc_f(mn[q]));
}

__global__ __launch_bounds__(256) void chamfer_reduce_kernel(
    const unsigned* __restrict__ minAB, const unsigned* __restrict__ minCD,
    float* __restrict__ acc)
{
  __shared__ float red[32];
  int s = blockIdx.x, dir = s>>2, b = s&3;
  const unsigned* mp; int len;
  if (dir==0){      mp=minAB + b*N0;            len=N0; }
  else if (dir==1){ mp=minAB + BB*N0 + b*N0;    len=N0; }
  else if (dir==2){ mp=minCD + b*NNEW;          len=NNEW; }
  else {            mp=minCD + BB*NNEW + b*N0;  len=N0; }
  float v = 0.f;
  for (int i=threadIdx.x;i<len;i+=256) v += dec_f(mp[i]);
  v = block_sum(v, red);
  if (threadIdx.x==0) acc[s] = v;
}

__global__ void finish_kernel(const float* __restrict__ acc, float* __restrict__ out)
{
  if (threadIdx.x == 0 && blockIdx.x == 0){
    float cd1 = 0.f, cd2 = 0.f;
    for (int b=0;b<BB;b++) cd1 += acc[b]/(float)N0 + acc[4+b]/(float)N0;
    for (int b=0;b<BB;b++) cd2 += acc[8+b]/(float)NNEW + acc[12+b]/(float)N0;
    out[0] = 0.1f*(cd1/BB) + 1.0f*(cd2/BB);
  }
}

extern "C" void kernel_launch(void* const* d_in, const int* in_sizes, int n_in,
                              void* d_out, int out_size, void* d_ws, size_t ws_size,
                              hipStream_t stream) {
  (void)in_sizes; (void)n_in; (void)out_size; (void)ws_size;
  const float* points   = (const float*)d_in[0];
  const float* gt       = (const float*)d_in[1];
  const float* enc_w1   = (const float*)d_in[2];
  const float* enc_b1   = (const float*)d_in[3];
  const float* enc_w2   = (const float*)d_in[4];
  const float* enc_b2   = (const float*)d_in[5];
  const float* enc_w3   = (const float*)d_in[6];
  const float* enc_b3   = (const float*)d_in[7];
  const float* att_w1   = (const float*)d_in[8];
  const float* att_b1   = (const float*)d_in[9];
  const float* att_w2   = (const float*)d_in[10];
  const float* att_b2   = (const float*)d_in[11];
  const float* lstm_wih = (const float*)d_in[12];
  const float* lstm_whh = (const float*)d_in[13];
  const float* lstm_bih = (const float*)d_in[14];
  const float* lstm_bhh = (const float*)d_in[15];
  const float* ref_w1   = (const float*)d_in[16];
  const float* ref_b1   = (const float*)d_in[17];
  const float* ref_w2   = (const float*)d_in[18];
  const float* ref_b2   = (const float*)d_in[19];
  float* out = (float*)d_out;

  float* ws      = (float*)d_ws;
  float* canvas  = ws + OFF_CANVAS;
  float* scoresb = ws + OFF_SCORES;
  float* d2b     = ws + OFF_D2;
  unsigned* gmaxp = (unsigned*)(ws + OFF_GMAX);
  float* hb      = ws + OFF_H;
  float* cb      = ws + OFF_C;
  float* acc     = ws + OFF_ACC;
  float* centerb = ws + OFF_CENTER;
  float* w2t     = ws + OFF_W2T;
  float* biasb   = ws + OFF_BIAS;
  float* f2buf   = ws + OFF_F2;

  prep_kernel<<<dim3(32), 256, 0, stream>>>(enc_w2, w2t);
  init_kernel<<<dim3(192), 256, 0, stream>>>(points, canvas, hb, cb, gmaxp);

  for (int t=0; t<NSTEPS; t++){
    int off = (t==0) ? 0 : (N0 + (t-1)*NEWP);
    int M   = (t==0) ? N0 : NEWP;
    int N   = N0 + t*NEWP;
    int nbM = (M + 255)/256;
    int nbN = (N + 255)/256;
    enc12_kernel<<<dim3(nbM, BB, 2), 256, 0, stream>>>(canvas, enc_w1, enc_b1, w2t, enc_b2, f2buf, off, M);
    enc3_kernel<<<dim3(nbM, BB, 4), 256, 0, stream>>>(f2buf, enc_w3, enc_b3, gmaxp, M);
    attbias_kernel<<<dim3(BB), 128, 0, stream>>>(att_w1, att_b1, gmaxp, hb, biasb);
    scores_kernel<<<dim3(nbN, BB), 256, 0, stream>>>(canvas, att_w1, att_w2, att_b2, biasb, scoresb, N);
    stepA_kernel<<<dim3(BB), 1024, 0, stream>>>(canvas, scoresb, d2b, gmaxp, hb, cb,
                                                lstm_wih, lstm_whh, lstm_bih, lstm_bhh, centerb, N);
    refine_kernel<<<dim3(14, BB), 256, 0, stream>>>(canvas, hb, centerb, ref_w1, ref_b1, ref_w2, ref_b2, N);
  }

  /* chamfer: reuse scoresb (minAB) and d2b (minCD) as per-x min arrays */
  unsigned* minAB = (unsigned*)scoresb;   /* 2*BB*N0 = 32768 <= BB*NMAX */
  unsigned* minCD = (unsigned*)d2b;       /* BB*(NNEW+N0) = 62464 = BB*NMAX */
  chamfer_init_kernel<<<dim3((BB*NMAX + 255)/256), 256, 0, stream>>>(minAB, minCD);
  chamfer_kernel<<<dim3(12, 12, 16), 256, 0, stream>>>(canvas, gt, minAB, minCD);
  chamfer_reduce_kernel<<<dim3(16), 256, 0, stream>>>(minAB, minCD, acc);
  finish_kernel<<<1, 64, 0, stream>>>(acc, out);
}

// Round 3
// 1480.865 us; speedup vs baseline: 2.3877x; 1.4619x over previous
//
#include <hip/hip_runtime.h>
#include <math.h>

#define BB 4
#define N0 4096
#define NEWP 1152
#define GD 256
#define HD 128
#define KSEL 64
#define NSTEPS 10
#define NMAX (N0 + NSTEPS*NEWP)   /* 15616 */
#define NNEW (NSTEPS*NEWP)        /* 11520 */
#define F2S (BB*N0)               /* 16384: stride of f2buf[k][b*N0+i] */

/* ---- workspace layout (float offsets) ---- */
#define OFF_CANVAS 0
#define OFF_MINAB  (OFF_CANVAS + BB*NMAX*3)   /* reused region (uint), 2*BB*N0 */
#define OFF_MINCD  (OFF_MINAB + BB*NMAX)      /* reused region (uint), BB*(NNEW+N0) */
#define OFF_GMAX   (OFF_MINCD + BB*NMAX)
#define OFF_H      (OFF_GMAX + BB*GD)
#define OFF_C      (OFF_H + BB*HD)
#define OFF_ACC    (OFF_C + BB*HD)
#define OFF_CENTER (OFF_ACC + 16)
#define OFF_W2T    (OFF_CENTER + 16)
#define OFF_PART   (OFF_W2T + 128*64)         /* BB*64*8 softmax partials */
#define OFF_F2     (OFF_PART + BB*64*8)
#define WS_FLOATS  (OFF_F2 + 128*F2S)

__device__ __forceinline__ unsigned enc_f(float f){
  unsigned u = __float_as_uint(f);
  return (u & 0x80000000u) ? ~u : (u | 0x80000000u);
}
__device__ __forceinline__ float dec_f(unsigned e){
  unsigned u = (e & 0x80000000u) ? (e & 0x7fffffffu) : ~e;
  return __uint_as_float(u);
}
__device__ __forceinline__ float sigm(float x){ return 1.f/(1.f+expf(-x)); }

__device__ __forceinline__ float block_sum(float v, volatile float* red){
#pragma unroll
  for (int s=32;s>0;s>>=1) v += __shfl_down(v, s, 64);
  int lane = threadIdx.x & 63, w = threadIdx.x >> 6, nw = blockDim.x >> 6;
  __syncthreads();
  if (lane==0) red[w] = v;
  __syncthreads();
  if (w==0){
    float x = (lane < nw) ? red[lane] : 0.f;
#pragma unroll
    for (int s=8;s>0;s>>=1) x += __shfl_down(x, s, 64);
    if (lane==0) red[0] = x;
  }
  __syncthreads();
  float r = red[0];
  __syncthreads();
  return r;
}
__device__ __forceinline__ float block_max(float v, volatile float* red){
#pragma unroll
  for (int s=32;s>0;s>>=1) v = fmaxf(v, __shfl_down(v, s, 64));
  int lane = threadIdx.x & 63, w = threadIdx.x >> 6, nw = blockDim.x >> 6;
  __syncthreads();
  if (lane==0) red[w] = v;
  __syncthreads();
  if (w==0){
    float x = (lane < nw) ? red[lane] : -3.4e38f;
#pragma unroll
    for (int s=8;s>0;s>>=1) x = fmaxf(x, __shfl_down(x, s, 64));
    if (lane==0) red[0] = x;
  }
  __syncthreads();
  float r = red[0];
  __syncthreads();
  return r;
}

/* transpose enc_w2 (64x128)->w2t[j*64+k] */
__global__ __launch_bounds__(256) void prep_kernel(
    const float* __restrict__ w2, float* __restrict__ w2t)
{
  int i = blockIdx.x*256 + threadIdx.x;
  if (i < 128*64){ int j = i>>6, k = i&63; w2t[i] = w2[k*128 + j]; }
}

__global__ __launch_bounds__(256) void init_kernel(
    const float* __restrict__ points, float* __restrict__ canvas,
    float* __restrict__ h, float* __restrict__ c,
    unsigned* __restrict__ gmax)
{
  int i = blockIdx.x*256 + threadIdx.x;
  if (i < BB*N0*3){
    int b = i / (N0*3);
    int r = i - b*(N0*3);
    canvas[(size_t)b*NMAX*3 + r] = points[i];
  }
  if (i < BB*HD){ h[i] = 0.f; c[i] = 0.f; }
  if (i < BB*GD) gmax[i] = 0u;
}

/* encoder layers 1+2; jc = quarter (32) of the 128 outputs */
__global__ __launch_bounds__(256) void enc12_kernel(
    const float* __restrict__ canvas, const float* __restrict__ w1,
    const float* __restrict__ b1, const float* __restrict__ w2t,
    const float* __restrict__ b2, float* __restrict__ f2buf,
    int off, int M)
{
  int b = blockIdx.y;
  int jc = blockIdx.z;
  int i = blockIdx.x*256 + threadIdx.x;
  int ii = (i < M) ? i : 0;
  const float* p = canvas + (size_t)(b*NMAX + off + ii)*3;
  float p0 = p[0], p1 = p[1], p2 = p[2];
  float f1[64];
#pragma unroll
  for (int j=0;j<64;j++)
    f1[j] = fmaxf(0.f, b1[j] + p0*w1[j] + p1*w1[64+j] + p2*w1[128+j]);
  int base = b*N0 + ii;
#pragma unroll
  for (int j=0;j<32;j++){
    int jo = jc*32 + j;
    float a = b2[jo];
    const float* wr = w2t + jo*64;
#pragma unroll
    for (int k=0;k<64;k++) a += f1[k]*wr[k];
    if (i < M) f2buf[(size_t)jo*F2S + base] = fmaxf(0.f, a);
  }
}

/* encoder layer 3 + running-max pool. dc = 32-dim chunk (8 chunks). */
__global__ __launch_bounds__(256) void enc3_kernel(
    const float* __restrict__ f2buf, const float* __restrict__ w3,
    const float* __restrict__ b3, unsigned* __restrict__ gmax, int M)
{
  int b = blockIdx.y;
  int dc = blockIdx.z;
  int i = blockIdx.x*256 + threadIdx.x;
  bool act = i < M;
  int ii = act ? i : 0;
  const float* fp = f2buf + b*N0 + ii;
  float a[32];
#pragma unroll
  for (int d0=0; d0<32; d0++) a[d0] = b3[dc*32 + d0];
  for (int k=0;k<128;k++){
    float fk = fp[(size_t)k*F2S];          /* coalesced */
    const float* wr = w3 + k*256 + dc*32;  /* wave-uniform -> scalar loads */
#pragma unroll
    for (int d0=0; d0<32; d0++) a[d0] += fk * wr[d0];
  }
#pragma unroll
  for (int d0=0; d0<32; d0++){
    float v = act ? a[d0] : -3.4e38f;
#pragma unroll
    for (int s2=32;s2>0;s2>>=1) v = fmaxf(v, __shfl_down(v, s2, 64));
    if ((threadIdx.x & 63) == 0) atomicMax(&gmax[b*GD + dc*32 + d0], enc_f(v));
  }
}

/* attention scores + per-block online-softmax partials (m, se, wx, wy, wz).
   Per-batch bias from gfeat/h computed in-block (tid<128). */
__global__ __launch_bounds__(256) void scores_kernel(
    const float* __restrict__ canvas, const float* __restrict__ aw1,
    const float* __restrict__ ab1, const float* __restrict__ aw2,
    const float* __restrict__ ab2, const unsigned* __restrict__ gmax,
    const float* __restrict__ h, float* __restrict__ part, int N)
{
  __shared__ float sBatt[128];
  __shared__ float red[8];
  int b = blockIdx.y;
  int tid = threadIdx.x;
  if (tid < 128){
    float a = ab1[tid];
    for (int k=0;k<GD;k++) a += dec_f(gmax[b*GD+k]) * aw1[(3+k)*128 + tid];
    for (int k=0;k<HD;k++) a += h[b*HD+k] * aw1[(3+GD+k)*128 + tid];
    sBatt[tid] = a;
  }
  __syncthreads();
  int i = blockIdx.x*256 + tid;
  bool act = i < N;
  float p0=0.f, p1=0.f, p2=0.f, s=-3.4e38f;
  if (act){
    const float* p = canvas + (size_t)(b*NMAX + i)*3;
    p0 = p[0]; p1 = p[1]; p2 = p[2];
    s = ab2[0];
    for (int j=0;j<128;j++){
      float t = sBatt[j] + p0*aw1[j] + p1*aw1[128+j] + p2*aw1[256+j];
      s += fmaxf(t, 0.f) * aw2[j];
    }
  }
  float mb = block_max(s, red);
  float e = act ? expf(s - mb) : 0.f;
  float se = block_sum(e, red);
  float wx = block_sum(e*p0, red);
  float wy = block_sum(e*p1, red);
  float wz = block_sum(e*p2, red);
  if (tid == 0){
    float* pp = part + (size_t)(b*64 + blockIdx.x)*8;
    pp[0]=mb; pp[1]=se; pp[2]=wx; pp[3]=wy; pp[4]=wz;
  }
}

/* per-batch: combine softmax partials -> center, register-resident radix
   top-64 patch mean, LSTM update. */
__global__ __launch_bounds__(1024, 4) void stepA_kernel(
    const float* __restrict__ canvas, const float* __restrict__ part,
    const unsigned* __restrict__ gmax,
    float* __restrict__ h, float* __restrict__ c,
    const float* __restrict__ wih, const float* __restrict__ whh,
    const float* __restrict__ bih, const float* __restrict__ bhh,
    float* __restrict__ centerbuf, int N, int nblk)
{
  __shared__ float red[32];
  __shared__ float sC[3], sPF[3];
  __shared__ unsigned hist[256];
  __shared__ unsigned scn[256];
  __shared__ int sSelBin, sSelK, tieCnt;
  __shared__ int tieIdx[256];
  __shared__ float sIn[GD+6];
  __shared__ float sHold[HD];
  __shared__ float sGates[4*HD];

  int b = blockIdx.x;
  int tid = threadIdx.x;
  const float* cv = canvas + (size_t)b*NMAX*3;

  /* --- phase 0: combine per-block softmax partials --- */
  float pm=-3.4e38f, pse=0.f, pwx=0.f, pwy=0.f, pwz=0.f;
  if (tid < nblk){
    const float* pp = part + (size_t)(b*64 + tid)*8;
    pm=pp[0]; pse=pp[1]; pwx=pp[2]; pwy=pp[3]; pwz=pp[4];
  }
  float M = block_max(pm, red);
  float w = (tid < nblk) ? expf(pm - M) : 0.f;
  float se = block_sum(pse*w, red);
  float wx = block_sum(pwx*w, red);
  float wy = block_sum(pwy*w, red);
  float wz = block_sum(pwz*w, red);
  if (tid==0){ sC[0]=wx/se; sC[1]=wy/se; sC[2]=wz/se; }
  __syncthreads();
  float cx=sC[0], cy=sC[1], cz=sC[2];
  if (tid<3) centerbuf[b*3+tid] = sC[tid];

  /* --- phase 1: load points into registers, compute d2 --- */
  float px[16], py[16], pz[16], d2r[16];
#pragma unroll
  for (int q=0;q<16;q++){
    int i = tid + q*1024;
    bool v = i < N;
    const float* p = cv + (size_t)(v?i:0)*3;
    px[q]=p[0]; py[q]=p[1]; pz[q]=p[2];
    float dx=px[q]-cx, dy=py[q]-cy, dz=pz[q]-cz;
    d2r[q] = v ? (dx*dx + dy*dy + dz*dz) : 3.3e38f;
  }

  /* --- radix select: 64th smallest d2 (bits monotonic for d2>=0) --- */
  int kneed = KSEL;
  unsigned prefix = 0;
  for (int pass=0; pass<4; pass++){
    int shift = 24 - 8*pass;
    if (tid < 256) hist[tid] = 0;
    __syncthreads();
#pragma unroll
    for (int q=0;q<16;q++){
      unsigned u = __float_as_uint(d2r[q]);
      bool ok = (pass==0) ? true : ((u >> (shift+8)) == prefix);
      if (ok) atomicAdd(&hist[(u>>shift)&255], 1u);
    }
    __syncthreads();
    /* parallel inclusive prefix scan over 256 bins */
    if (tid < 256) scn[tid] = hist[tid];
    __syncthreads();
    for (int off=1; off<256; off<<=1){
      unsigned add = 0;
      if (tid < 256 && tid >= off) add = scn[tid-off];
      __syncthreads();
      if (tid < 256) scn[tid] += add;
      __syncthreads();
    }
    if (tid < 256){
      int cum = (int)scn[tid];
      int prev = (tid==0) ? 0 : (int)scn[tid-1];
      if (cum >= kneed && prev < kneed){ sSelBin = tid; sSelK = kneed - prev; }
    }
    __syncthreads();
    prefix = (prefix<<8) | (unsigned)sSelBin;
    kneed = sSelK;
    __syncthreads();
  }
  unsigned T = prefix;

  if (tid==0) tieCnt = 0;
  __syncthreads();
  float sx=0.f, sy=0.f, sz=0.f;
#pragma unroll
  for (int q=0;q<16;q++){
    unsigned u = __float_as_uint(d2r[q]);
    if (u < T){
      sx += px[q]; sy += py[q]; sz += pz[q];
    } else if (u == T){
      int pos = atomicAdd(&tieCnt, 1);
      if (pos < 256) tieIdx[pos] = tid + q*1024;
    }
  }
  __syncthreads();
  sx = block_sum(sx, red);
  sy = block_sum(sy, red);
  sz = block_sum(sz, red);
  if (tid==0){
    int mm = tieCnt < 256 ? tieCnt : 256;
    for (int t=0;t<kneed;t++){
      int best=-1, bi=0x7fffffff;
      for (int q=0;q<mm;q++){ int v = tieIdx[q]; if (v < bi){ bi=v; best=q; } }
      if (best >= 0){
        tieIdx[best] = 0x7fffffff;
        const float* p = cv + (size_t)bi*3;
        sx += p[0]; sy += p[1]; sz += p[2];
      }
    }
    sPF[0] = sx/KSEL - cx; sPF[1] = sy/KSEL - cy; sPF[2] = sz/KSEL - cz;
  }
  __syncthreads();

  /* --- LSTM --- */
  if (tid < GD) sIn[tid] = dec_f(gmax[b*GD + tid]);
  else if (tid < GD+3) sIn[tid] = sC[tid-GD];
  else if (tid < GD+6) sIn[tid] = sPF[tid-GD-3];
  if (tid < HD) sHold[tid] = h[b*HD + tid];
  __syncthreads();
  if (tid < 4*HD){
    float a = bih[tid] + bhh[tid];
    for (int k=0;k<GD+6;k++) a += sIn[k]*wih[k*(4*HD) + tid];
    for (int k=0;k<HD;k++)   a += sHold[k]*whh[k*(4*HD) + tid];
    sGates[tid] = a;
  }
  __syncthreads();
  if (tid < HD){
    float gi = sGates[tid], gf = sGates[HD+tid], gg = sGates[2*HD+tid], go = sGates[3*HD+tid];
    float cn = sigm(gf)*c[b*HD+tid] + sigm(gi)*tanhf(gg);
    float hn = sigm(go)*tanhf(cn);
    c[b*HD+tid] = cn;
    h[b*HD+tid] = hn;
  }
}

/* refinement decoder */
__global__ __launch_bounds__(256) void refine_kernel(
    float* __restrict__ canvas, const float* __restrict__ h,
    const float* __restrict__ centerbuf,
    const float* __restrict__ rw1, const float* __restrict__ rb1,
    const float* __restrict__ rw2, const float* __restrict__ rb2, int N)
{
  __shared__ float sRf[HD];
  int b = blockIdx.y;
  int tid = threadIdx.x;
  if (tid < HD){
    float a = rb1[tid];
    for (int k=0;k<HD;k++) a += h[b*HD+k]*rw1[k*HD + tid];
    sRf[tid] = fmaxf(a, 0.f);
  }
  __syncthreads();
  int o = blockIdx.x*256 + tid;
  if (o < NEWP*3){
    float a = rb2[o];
    for (int k=0;k<HD;k++) a += sRf[k]*rw2[k*(NEWP*3) + o];
    canvas[((size_t)b*NMAX + N)*3 + o] = a*0.02f + centerbuf[b*3 + (o%3)];
  }
}

/* ---- chamfer: dot form, SoA LDS y-tiles, flat 256-block grid ---- */
#define CYT 1024

__global__ __launch_bounds__(256) void chamfer_init_kernel(
    unsigned* __restrict__ minAB, unsigned* __restrict__ minCD)
{
  int i = blockIdx.x*256 + threadIdx.x;
  if (i < 2*BB*N0) minAB[i] = 0xFFFFFFFFu;
  if (i < BB*NNEW + BB*N0) minCD[i] = 0xFFFFFFFFu;
}

__global__ __launch_bounds__(512) void chamfer_kernel(
    const float* __restrict__ canvas, const float* __restrict__ gt,
    unsigned* __restrict__ minAB, unsigned* __restrict__ minCD)
{
  __shared__ float sy0[CYT], sy1[CYT], sy2[CYT], sny[CYT];
  int id = blockIdx.x;   /* 0..255, all valid */
  int dir, rem;
  if (id < 32){ dir=0; rem=id; }
  else if (id < 64){ dir=1; rem=id-32; }
  else if (id < 160){ dir=2; rem=id-64; }
  else { dir=3; rem=id-160; }
  int b, xb, yb;
  if (dir < 2){ b = rem>>3; int l = rem&7; xb = l>>2; yb = l&3; }        /* 2x4 */
  else if (dir == 2){ b = rem/24; int l = rem%24; xb = l>>2; yb = l&3; } /* 6x4 */
  else { b = rem/24; int l = rem%24; xb = l/12; yb = l%12; }             /* 2x12 */

  int Nx, Ny; const float* X; const float* Y; unsigned* mp;
  if (dir==0){      Nx=N0;   Ny=N0;   X=canvas+(size_t)b*NMAX*3;       Y=gt+(size_t)b*N0*3;            mp=minAB + b*N0; }
  else if (dir==1){ Nx=N0;   Ny=N0;   X=gt+(size_t)b*N0*3;             Y=canvas+(size_t)b*NMAX*3;      mp=minAB + BB*N0 + b*N0; }
  else if (dir==2){ Nx=NNEW; Ny=N0;   X=canvas+((size_t)b*NMAX+N0)*3;  Y=gt+(size_t)b*N0*3;            mp=minCD + b*NNEW; }
  else {            Nx=N0;   Ny=NNEW; X=gt+(size_t)b*N0*3;             Y=canvas+((size_t)b*NMAX+N0)*3; mp=minCD + BB*NNEW + b*N0; }

  int xbase = xb*2048;
  int ybase = yb*CYT;
  int tn = min(CYT, Ny - ybase);
  int tid = threadIdx.x;
  for (int t=tid; t<tn; t+=512){
    const float* yp = Y + (size_t)(ybase+t)*3;
    float y0=yp[0], y1=yp[1], y2=yp[2];
    sy0[t]=y0; sy1[t]=y1; sy2[t]=y2; sny[t]=y0*y0+y1*y1+y2*y2;
  }
  __syncthreads();

  float X0[4],X1[4],X2[4],NXr[4],MN[4]; int XI[4]; bool VA[4];
#pragma unroll
  for (int q=0;q<4;q++){
    int x = xbase + q*512 + tid;
    VA[q] = x < Nx;
    int xc = VA[q] ? x : 0;
    const float* xp = X + (size_t)xc*3;
    X0[q]=xp[0]; X1[q]=xp[1]; X2[q]=xp[2];
    NXr[q] = X0[q]*X0[q] + X1[q]*X1[q] + X2[q]*X2[q];
    MN[q] = 3.4e38f; XI[q] = xc;
  }
  const float4* v0 = (const float4*)sy0;
  const float4* v1 = (const float4*)sy1;
  const float4* v2 = (const float4*)sy2;
  const float4* vn = (const float4*)sny;
  int j4n = tn >> 2;
  for (int j=0;j<j4n;j++){
    float4 a0 = v0[j], a1 = v1[j], a2 = v2[j], an = vn[j];
#pragma unroll
    for (int e=0;e<4;e++){
      float y0 = ((const float*)&a0)[e];
      float y1 = ((const float*)&a1)[e];
      float y2 = ((const float*)&a2)[e];
      float ny = ((const float*)&an)[e];
#pragma unroll
      for (int q=0;q<4;q++){
        float dot = fmaf(X0[q], y0, fmaf(X1[q], y1, X2[q]*y2));
        float d   = fmaf(-2.f, dot, ny);
        MN[q] = fminf(MN[q], d);
      }
    }
  }
  for (int j=j4n*4; j<tn; j++){
    float y0=sy0[j], y1=sy1[j], y2=sy2[j], ny=sny[j];
#pragma unroll
    for (int q=0;q<4;q++){
      float dot = fmaf(X0[q], y0, fmaf(X1[q], y1, X2[q]*y2));
      MN[q] = fminf(MN[q], fmaf(-2.f, dot, ny));
    }
  }
#pragma unroll
  for (int q=0;q<4;q++)
    if (VA[q]) atomicMin(&mp[XI[q]], enc_f(MN[q] + NXr[q]));
}

__global__ __launch_bounds__(256) void chamfer_reduce_kernel(
    const unsigned* __restrict__ minAB, const unsigned* __restrict__ minCD,
    float* __restrict__ acc)
{
  __shared__ float red[8];
  int s = blockIdx.x, dir = s>>2, b = s&3;
  const unsigned* mp; int len;
  if (dir==0){      mp=minAB + b*N0;            len=N0; }
  else if (dir==1){ mp=minAB + BB*N0 + b*N0;    len=N0; }
  else if (dir==2){ mp=minCD + b*NNEW;          len=NNEW; }
  else {            mp=minCD + BB*NNEW + b*N0;  len=N0; }
  float v = 0.f;
  for (int i=threadIdx.x;i<len;i+=256) v += dec_f(mp[i]);
  v = block_sum(v, red);
  if (threadIdx.x==0) acc[s] = v;
}

__global__ void finish_kernel(const float* __restrict__ acc, float* __restrict__ out)
{
  if (threadIdx.x == 0 && blockIdx.x == 0){
    float cd1 = 0.f, cd2 = 0.f;
    for (int b=0;b<BB;b++) cd1 += acc[b]/(float)N0 + acc[4+b]/(float)N0;
    for (int b=0;b<BB;b++) cd2 += acc[8+b]/(float)NNEW + acc[12+b]/(float)N0;
    out[0] = 0.1f*(cd1/BB) + 1.0f*(cd2/BB);
  }
}

extern "C" void kernel_launch(void* const* d_in, const int* in_sizes, int n_in,
                              void* d_out, int out_size, void* d_ws, size_t ws_size,
                              hipStream_t stream) {
  (void)in_sizes; (void)n_in; (void)out_size; (void)ws_size;
  const float* points   = (const float*)d_in[0];
  const float* gt       = (const float*)d_in[1];
  const float* enc_w1   = (const float*)d_in[2];
  const float* enc_b1   = (const float*)d_in[3];
  const float* enc_w2   = (const float*)d_in[4];
  const float* enc_b2   = (const float*)d_in[5];
  const float* enc_w3   = (const float*)d_in[6];
  const float* enc_b3   = (const float*)d_in[7];
  const float* att_w1   = (const float*)d_in[8];
  const float* att_b1   = (const float*)d_in[9];
  const float* att_w2   = (const float*)d_in[10];
  const float* att_b2   = (const float*)d_in[11];
  const float* lstm_wih = (const float*)d_in[12];
  const float* lstm_whh = (const float*)d_in[13];
  const float* lstm_bih = (const float*)d_in[14];
  const float* lstm_bhh = (const float*)d_in[15];
  const float* ref_w1   = (const float*)d_in[16];
  const float* ref_b1   = (const float*)d_in[17];
  const float* ref_w2   = (const float*)d_in[18];
  const float* ref_b2   = (const float*)d_in[19];
  float* out = (float*)d_out;

  float* ws      = (float*)d_ws;
  float* canvas  = ws + OFF_CANVAS;
  unsigned* minAB = (unsigned*)(ws + OFF_MINAB);
  unsigned* minCD = (unsigned*)(ws + OFF_MINCD);
  unsigned* gmaxp = (unsigned*)(ws + OFF_GMAX);
  float* hb      = ws + OFF_H;
  float* cb      = ws + OFF_C;
  float* acc     = ws + OFF_ACC;
  float* centerb = ws + OFF_CENTER;
  float* w2t     = ws + OFF_W2T;
  float* partb   = ws + OFF_PART;
  float* f2buf   = ws + OFF_F2;

  prep_kernel<<<dim3(32), 256, 0, stream>>>(enc_w2, w2t);
  init_kernel<<<dim3(192), 256, 0, stream>>>(points, canvas, hb, cb, gmaxp);

  for (int t=0; t<NSTEPS; t++){
    int off = (t==0) ? 0 : (N0 + (t-1)*NEWP);
    int M   = (t==0) ? N0 : NEWP;
    int N   = N0 + t*NEWP;
    int nbM = (M + 255)/256;
    int nbN = (N + 255)/256;
    enc12_kernel<<<dim3(nbM, BB, 4), 256, 0, stream>>>(canvas, enc_w1, enc_b1, w2t, enc_b2, f2buf, off, M);
    enc3_kernel<<<dim3(nbM, BB, 8), 256, 0, stream>>>(f2buf, enc_w3, enc_b3, gmaxp, M);
    scores_kernel<<<dim3(nbN, BB), 256, 0, stream>>>(canvas, att_w1, att_b1, att_w2, att_b2, gmaxp, hb, partb, N);
    stepA_kernel<<<dim3(BB), 1024, 0, stream>>>(canvas, partb, gmaxp, hb, cb,
                                                lstm_wih, lstm_whh, lstm_bih, lstm_bhh, centerb, N, nbN);
    refine_kernel<<<dim3(14, BB), 256, 0, stream>>>(canvas, hb, centerb, ref_w1, ref_b1, ref_w2, ref_b2, N);
  }

  chamfer_init_kernel<<<dim3((BB*NMAX + 255)/256), 256, 0, stream>>>(minAB, minCD);
  chamfer_kernel<<<dim3(256), 512, 0, stream>>>(canvas, gt, minAB, minCD);
  chamfer_reduce_kernel<<<dim3(16), 256, 0, stream>>>(minAB, minCD, acc);
  finish_kernel<<<1, 64, 0, stream>>>(acc, out);
}